// Round 1
// baseline (301.235 us; speedup 1.0000x reference)
//
#include <hip/hip_runtime.h>
#include <hip/hip_bf16.h>

#define NB 64          // batch
#define NPIX 65536     // 256*256
#define NCLS 4
#define NPATCH 64
#define TOPK 16

// ---------------- workspace layout (floats) ----------------
// acc   : [64][12]  (inter[4], sumS[4], cnt[4])      at ws + 0
// omean : [64][64]                                    at ws + 1024
// amean : [64][64]                                    at ws + 5120
// srcmap: [64][64]  (int)                             at ws + 9216

__global__ void k_zero(float* __restrict__ acc) {
    int i = blockIdx.x * 256 + threadIdx.x;
    if (i < NB * 12) acc[i] = 0.f;
}

__device__ __forceinline__ void px_acc(float p0, float p1, float p2, float p3, int t,
                                       float& i0, float& i1, float& i2, float& i3,
                                       float& s0, float& s1, float& s2, float& s3,
                                       float& c0, float& c1, float& c2, float& c3) {
    float m  = fmaxf(fmaxf(p0, p1), fmaxf(p2, p3));
    float e0 = expf(p0 - m), e1 = expf(p1 - m), e2 = expf(p2 - m), e3 = expf(p3 - m);
    float inv = 1.f / (e0 + e1 + e2 + e3);
    float q0 = e0 * inv, q1 = e1 * inv, q2 = e2 * inv, q3 = e3 * inv;
    s0 += q0; s1 += q1; s2 += q2; s3 += q3;
    i0 += (t == 0) ? q0 : 0.f;
    i1 += (t == 1) ? q1 : 0.f;
    i2 += (t == 2) ? q2 : 0.f;
    i3 += (t == 3) ? q3 : 0.f;
    c0 += (float)(t == 0); c1 += (float)(t == 1);
    c2 += (float)(t == 2); c3 += (float)(t == 3);
}

// grid (NB, 8), block 256: per-class inter / sum-softmax / count partial sums
__global__ void k_dice(const float* __restrict__ pred, const int* __restrict__ lab,
                       float* __restrict__ acc) {
    const int b     = blockIdx.x;
    const int chunk = blockIdx.y;
    const int tid   = threadIdx.x;
    const float* pb = pred + (size_t)b * NCLS * NPIX;
    const int*   lb = lab  + (size_t)b * NPIX;
    const float4* P0 = (const float4*)pb;
    const float4* P1 = (const float4*)(pb + NPIX);
    const float4* P2 = (const float4*)(pb + 2 * NPIX);
    const float4* P3 = (const float4*)(pb + 3 * NPIX);
    const int4*   L  = (const int4*)lb;

    float i0 = 0, i1 = 0, i2 = 0, i3 = 0;
    float s0 = 0, s1 = 0, s2 = 0, s3 = 0;
    float c0 = 0, c1 = 0, c2 = 0, c3 = 0;

    #pragma unroll
    for (int it = 0; it < 8; ++it) {
        int i4 = chunk * 2048 + it * 256 + tid;
        float4 a = P0[i4], b4 = P1[i4], c4 = P2[i4], d4 = P3[i4];
        int4 lv = L[i4];
        px_acc(a.x, b4.x, c4.x, d4.x, lv.x, i0, i1, i2, i3, s0, s1, s2, s3, c0, c1, c2, c3);
        px_acc(a.y, b4.y, c4.y, d4.y, lv.y, i0, i1, i2, i3, s0, s1, s2, s3, c0, c1, c2, c3);
        px_acc(a.z, b4.z, c4.z, d4.z, lv.z, i0, i1, i2, i3, s0, s1, s2, s3, c0, c1, c2, c3);
        px_acc(a.w, b4.w, c4.w, d4.w, lv.w, i0, i1, i2, i3, s0, s1, s2, s3, c0, c1, c2, c3);
    }

    float vals[12] = {i0, i1, i2, i3, s0, s1, s2, s3, c0, c1, c2, c3};
    #pragma unroll
    for (int j = 0; j < 12; ++j) {
        float v = vals[j];
        #pragma unroll
        for (int off = 32; off > 0; off >>= 1) v += __shfl_down(v, off, 64);
        if ((tid & 63) == 0) atomicAdd(&acc[b * 12 + j], v);
    }
}

// grid (8 blockrows, 2 which, NB), block 256: per-patch conf means
__global__ void k_conf(const float* __restrict__ oconf, const float* __restrict__ aconf,
                       float* __restrict__ omean, float* __restrict__ amean) {
    const int br    = blockIdx.x;   // patch row block (8 patches)
    const int which = blockIdx.y;
    const int b     = blockIdx.z;
    const int tid   = threadIdx.x;
    const float* src = which ? aconf : oconf;
    const float4* s4 = (const float4*)(src + (size_t)b * NPIX + br * 32 * 256);
    const int f4c = tid & 63;   // float4 column 0..63
    const int r0  = tid >> 6;   // row offset 0..3

    float s = 0.f;
    #pragma unroll
    for (int it = 0; it < 8; ++it) {
        float4 v = s4[(r0 + it * 4) * 64 + f4c];
        s += v.x + v.y + v.z + v.w;
    }
    __shared__ float psum[8];
    if (tid < 8) psum[tid] = 0.f;
    __syncthreads();
    atomicAdd(&psum[f4c >> 3], s);
    __syncthreads();
    if (tid < 8) {
        float* dst = which ? amean : omean;
        dst[b * 64 + br * 8 + tid] = psum[tid] * (1.0f / 1024.0f);
    }
}

// grid NB, block 64: loss -> k, stable argsort, srcmap
__global__ void k_sortmap(const float* __restrict__ acc,
                          const float* __restrict__ omean, const float* __restrict__ amean,
                          int* __restrict__ srcmap) {
    const int b   = blockIdx.x;
    const int tid = threadIdx.x;   // 0..63
    const float* ac = acc + b * 12;

    float dice = 0.f;
    #pragma unroll
    for (int c = 0; c < 4; ++c) {
        float inter = ac[c], sumS = ac[4 + c], cnt = ac[8 + c];
        dice += 2.f * inter / (sumS + cnt + 1e-5f);
    }
    float loss = 1.f - dice * 0.25f;
    bool  sp   = loss < 1.0f;                 // AGE = 1.0
    float sign = sp ? -1.f : 1.f;
    float spw  = 1.f - loss / (1.0f + 1e-5f);
    int   k    = min(TOPK, (int)fabsf(truncf((float)TOPK * spw)));

    __shared__ float keyo[64], keya[64];
    __shared__ int   oidx[64], aidx[64];
    float ko = sign  * omean[b * 64 + tid];
    float ka = -sign * amean[b * 64 + tid];
    keyo[tid] = ko; keya[tid] = ka;
    __syncthreads();

    int ro = 0, ra = 0;
    for (int j = 0; j < 64; ++j) {
        float kj = keyo[j];
        ro += (kj < ko || (kj == ko && j < tid)) ? 1 : 0;
        float k2 = keya[j];
        ra += (k2 < ka || (k2 == ka && j < tid)) ? 1 : 0;
    }
    oidx[ro] = tid;   // ascending stable argsort of keyo
    aidx[ra] = tid;
    __syncthreads();

    int pos = oidx[tid];
    srcmap[b * 64 + pos] = (tid < k) ? aidx[tid] : -1;
}

// grid (64, 5, NB), block 256: patch-remapped copy to packed output
__global__ void k_assemble(const float* __restrict__ oimage, const float* __restrict__ aimage,
                           const int* __restrict__ olabel, const int* __restrict__ alabel,
                           const float* __restrict__ oconf, const float* __restrict__ aconf,
                           const int* __restrict__ srcmap, float* __restrict__ out) {
    const int b  = blockIdx.z;
    const int ch = blockIdx.y;                       // 0..2 image, 3 label, 4 conf
    const int f4 = blockIdx.x * 256 + threadIdx.x;   // 0..16383
    const int pix = f4 << 2;
    const int y = pix >> 8, x = pix & 255;
    const int p = ((y >> 5) << 3) + (x >> 5);
    const int m = srcmap[(b << 6) + p];
    const bool aug = (m >= 0);
    int sy = y, sx = x;
    if (aug) { sy = ((m >> 3) << 5) + (y & 31); sx = ((m & 7) << 5) + (x & 31); }
    const int sidx4 = ((sy << 8) + sx) >> 2;
    const size_t bplane = (size_t)b << 16;

    if (ch < 3) {
        const size_t plane = (size_t)(b * 3 + ch) << 16;
        const float4* src = (const float4*)((aug ? aimage : oimage) + plane);
        ((float4*)(out + plane))[f4] = src[sidx4];
    } else if (ch == 3) {
        const int4* src = (const int4*)((aug ? alabel : olabel) + bplane);
        int4 v = src[sidx4];
        float4 w = make_float4((float)v.x, (float)v.y, (float)v.z, (float)v.w);
        ((float4*)(out + 12582912 + bplane))[f4] = w;
    } else {
        const float4* src = (const float4*)((aug ? aconf : oconf) + bplane);
        ((float4*)(out + 16777216 + bplane))[f4] = src[sidx4];
    }
}

extern "C" void kernel_launch(void* const* d_in, const int* in_sizes, int n_in,
                              void* d_out, int out_size, void* d_ws, size_t ws_size,
                              hipStream_t stream) {
    const float* oimage = (const float*)d_in[0];
    const float* aimage = (const float*)d_in[1];
    const int*   olabel = (const int*)d_in[2];
    const int*   alabel = (const int*)d_in[3];
    const float* oconf  = (const float*)d_in[4];
    const float* aconf  = (const float*)d_in[5];
    const float* pred   = (const float*)d_in[6];
    // d_in[7] = cur_step (unused by the taken branch)

    float* ws     = (float*)d_ws;
    float* acc    = ws;                 // 768 floats
    float* omean  = ws + 1024;          // 4096 floats
    float* amean  = ws + 5120;          // 4096 floats
    int*   srcmap = (int*)(ws + 9216);  // 4096 ints

    float* out = (float*)d_out;

    hipLaunchKernelGGL(k_zero,     dim3(3),           dim3(256), 0, stream, acc);
    hipLaunchKernelGGL(k_dice,     dim3(NB, 8),       dim3(256), 0, stream, pred, olabel, acc);
    hipLaunchKernelGGL(k_conf,     dim3(8, 2, NB),    dim3(256), 0, stream, oconf, aconf, omean, amean);
    hipLaunchKernelGGL(k_sortmap,  dim3(NB),          dim3(64),  0, stream, acc, omean, amean, srcmap);
    hipLaunchKernelGGL(k_assemble, dim3(64, 5, NB),   dim3(256), 0, stream,
                       oimage, aimage, olabel, alabel, oconf, aconf, srcmap, out);
}

// Round 2
// 255.149 us; speedup vs baseline: 1.1806x; 1.1806x over previous
//
#include <hip/hip_runtime.h>
#include <hip/hip_bf16.h>

#define NB 64          // batch
#define NPIX 65536     // 256*256
#define NCLS 4
#define NPATCH 64
#define TOPK 16

// ---------------- workspace layout (floats) ----------------
// part  : [64][32][12] dice partials (inter[4], sumS[4], cnt[4])  at ws + 0      (24576)
// omean : [64][64]                                                 at ws + 24576 (4096)
// amean : [64][64]                                                 at ws + 28672 (4096)
// srcmap: [64][64] (int)                                           at ws + 32768 (4096)

__device__ __forceinline__ void px_acc(float p0, float p1, float p2, float p3, int t,
                                       float& i0, float& i1, float& i2, float& i3,
                                       float& s0, float& s1, float& s2, float& s3,
                                       float& c0, float& c1, float& c2, float& c3) {
    float m  = fmaxf(fmaxf(p0, p1), fmaxf(p2, p3));
    float e0 = __expf(p0 - m), e1 = __expf(p1 - m), e2 = __expf(p2 - m), e3 = __expf(p3 - m);
    float inv = 1.f / (e0 + e1 + e2 + e3);
    float q0 = e0 * inv, q1 = e1 * inv, q2 = e2 * inv, q3 = e3 * inv;
    s0 += q0; s1 += q1; s2 += q2; s3 += q3;
    i0 += (t == 0) ? q0 : 0.f;
    i1 += (t == 1) ? q1 : 0.f;
    i2 += (t == 2) ? q2 : 0.f;
    i3 += (t == 3) ? q3 : 0.f;
    c0 += (float)(t == 0); c1 += (float)(t == 1);
    c2 += (float)(t == 2); c3 += (float)(t == 3);
}

// grid 3072 blocks of 256:
//   blocks [0,2048): dice partials, b = bid>>5, chunk = bid&31 (512 float4 per chunk)
//   blocks [2048,3072): per-patch conf means, cid = bid-2048: br=cid%8, which=(cid>>3)&1, b=cid>>4
__global__ void k_stage1(const float* __restrict__ pred, const int* __restrict__ lab,
                         const float* __restrict__ oconf, const float* __restrict__ aconf,
                         float* __restrict__ part, float* __restrict__ omean,
                         float* __restrict__ amean) {
    __shared__ float smem[48];
    const int bid = blockIdx.x;
    const int tid = threadIdx.x;

    if (bid < 2048) {
        const int b     = bid >> 5;
        const int chunk = bid & 31;
        const float* pb = pred + (size_t)b * NCLS * NPIX;
        const float4* P0 = (const float4*)pb;
        const float4* P1 = (const float4*)(pb + NPIX);
        const float4* P2 = (const float4*)(pb + 2 * NPIX);
        const float4* P3 = (const float4*)(pb + 3 * NPIX);
        const int4*   L  = (const int4*)(lab + (size_t)b * NPIX);

        float i0 = 0, i1 = 0, i2 = 0, i3 = 0;
        float s0 = 0, s1 = 0, s2 = 0, s3 = 0;
        float c0 = 0, c1 = 0, c2 = 0, c3 = 0;

        #pragma unroll
        for (int it = 0; it < 2; ++it) {
            int i4 = chunk * 512 + it * 256 + tid;
            float4 a = P0[i4], b4 = P1[i4], c4 = P2[i4], d4 = P3[i4];
            int4 lv = L[i4];
            px_acc(a.x, b4.x, c4.x, d4.x, lv.x, i0, i1, i2, i3, s0, s1, s2, s3, c0, c1, c2, c3);
            px_acc(a.y, b4.y, c4.y, d4.y, lv.y, i0, i1, i2, i3, s0, s1, s2, s3, c0, c1, c2, c3);
            px_acc(a.z, b4.z, c4.z, d4.z, lv.z, i0, i1, i2, i3, s0, s1, s2, s3, c0, c1, c2, c3);
            px_acc(a.w, b4.w, c4.w, d4.w, lv.w, i0, i1, i2, i3, s0, s1, s2, s3, c0, c1, c2, c3);
        }

        float vals[12] = {i0, i1, i2, i3, s0, s1, s2, s3, c0, c1, c2, c3};
        const int wave = tid >> 6, lane = tid & 63;
        #pragma unroll
        for (int j = 0; j < 12; ++j) {
            float v = vals[j];
            #pragma unroll
            for (int off = 32; off > 0; off >>= 1) v += __shfl_down(v, off, 64);
            if (lane == 0) smem[wave * 12 + j] = v;
        }
        __syncthreads();
        if (tid < 12)
            part[(b * 32 + chunk) * 12 + tid] =
                smem[tid] + smem[12 + tid] + smem[24 + tid] + smem[36 + tid];
    } else {
        const int cid   = bid - 2048;
        const int br    = cid & 7;          // patch row block (8 patches)
        const int which = (cid >> 3) & 1;
        const int b     = cid >> 4;
        const float* src = which ? aconf : oconf;
        const float4* s4 = (const float4*)(src + (size_t)b * NPIX + br * 32 * 256);
        const int f4c = tid & 63;   // float4 column 0..63
        const int r0  = tid >> 6;   // row offset 0..3

        float s = 0.f;
        #pragma unroll
        for (int it = 0; it < 8; ++it) {
            float4 v = s4[(r0 + it * 4) * 64 + f4c];
            s += v.x + v.y + v.z + v.w;
        }
        if (tid < 8) smem[tid] = 0.f;
        __syncthreads();
        atomicAdd(&smem[f4c >> 3], s);
        __syncthreads();
        if (tid < 8) {
            float* dst = which ? amean : omean;
            dst[b * 64 + br * 8 + tid] = smem[tid] * (1.0f / 1024.0f);
        }
    }
}

// grid NB, block 64: reduce partials -> loss -> k, stable argsort, srcmap
__global__ void k_sortmap(const float* __restrict__ part,
                          const float* __restrict__ omean, const float* __restrict__ amean,
                          int* __restrict__ srcmap) {
    const int b   = blockIdx.x;
    const int tid = threadIdx.x;   // 0..63

    __shared__ float accs[12];
    if (tid < 12) {
        float s = 0.f;
        #pragma unroll
        for (int c = 0; c < 32; ++c) s += part[(b * 32 + c) * 12 + tid];
        accs[tid] = s;
    }
    __syncthreads();

    float dice = 0.f;
    #pragma unroll
    for (int c = 0; c < 4; ++c)
        dice += 2.f * accs[c] / (accs[4 + c] + accs[8 + c] + 1e-5f);
    float loss = 1.f - dice * 0.25f;
    bool  sp   = loss < 1.0f;                 // AGE = 1.0
    float sign = sp ? -1.f : 1.f;
    float spw  = 1.f - loss / (1.0f + 1e-5f);
    int   k    = min(TOPK, (int)fabsf(truncf((float)TOPK * spw)));

    __shared__ float keyo[64], keya[64];
    __shared__ int   oidx[64], aidx[64];
    float ko = sign  * omean[b * 64 + tid];
    float ka = -sign * amean[b * 64 + tid];
    keyo[tid] = ko; keya[tid] = ka;
    __syncthreads();

    int ro = 0, ra = 0;
    for (int j = 0; j < 64; ++j) {
        float kj = keyo[j];
        ro += (kj < ko || (kj == ko && j < tid)) ? 1 : 0;
        float k2 = keya[j];
        ra += (k2 < ka || (k2 == ka && j < tid)) ? 1 : 0;
    }
    oidx[ro] = tid;   // ascending stable argsort of keyo
    aidx[ra] = tid;
    __syncthreads();

    int pos = oidx[tid];
    srcmap[b * 64 + pos] = (tid < k) ? aidx[tid] : -1;
}

// grid (64, 5, NB), block 256: patch-remapped copy to packed output
__global__ void k_assemble(const float* __restrict__ oimage, const float* __restrict__ aimage,
                           const int* __restrict__ olabel, const int* __restrict__ alabel,
                           const float* __restrict__ oconf, const float* __restrict__ aconf,
                           const int* __restrict__ srcmap, float* __restrict__ out) {
    const int b  = blockIdx.z;
    const int ch = blockIdx.y;                       // 0..2 image, 3 label, 4 conf
    const int f4 = blockIdx.x * 256 + threadIdx.x;   // 0..16383
    const int pix = f4 << 2;
    const int y = pix >> 8, x = pix & 255;
    const int p = ((y >> 5) << 3) + (x >> 5);
    const int m = srcmap[(b << 6) + p];
    const bool aug = (m >= 0);
    int sy = y, sx = x;
    if (aug) { sy = ((m >> 3) << 5) + (y & 31); sx = ((m & 7) << 5) + (x & 31); }
    const int sidx4 = ((sy << 8) + sx) >> 2;
    const size_t bplane = (size_t)b << 16;

    if (ch < 3) {
        const size_t plane = (size_t)(b * 3 + ch) << 16;
        const float4* src = (const float4*)((aug ? aimage : oimage) + plane);
        ((float4*)(out + plane))[f4] = src[sidx4];
    } else if (ch == 3) {
        const int4* src = (const int4*)((aug ? alabel : olabel) + bplane);
        int4 v = src[sidx4];
        float4 w = make_float4((float)v.x, (float)v.y, (float)v.z, (float)v.w);
        ((float4*)(out + 12582912 + bplane))[f4] = w;
    } else {
        const float4* src = (const float4*)((aug ? aconf : oconf) + bplane);
        ((float4*)(out + 16777216 + bplane))[f4] = src[sidx4];
    }
}

extern "C" void kernel_launch(void* const* d_in, const int* in_sizes, int n_in,
                              void* d_out, int out_size, void* d_ws, size_t ws_size,
                              hipStream_t stream) {
    const float* oimage = (const float*)d_in[0];
    const float* aimage = (const float*)d_in[1];
    const int*   olabel = (const int*)d_in[2];
    const int*   alabel = (const int*)d_in[3];
    const float* oconf  = (const float*)d_in[4];
    const float* aconf  = (const float*)d_in[5];
    const float* pred   = (const float*)d_in[6];
    // d_in[7] = cur_step (unused by the taken branch)

    float* ws     = (float*)d_ws;
    float* part   = ws;                  // 24576 floats
    float* omean  = ws + 24576;          // 4096 floats
    float* amean  = ws + 28672;          // 4096 floats
    int*   srcmap = (int*)(ws + 32768);  // 4096 ints

    float* out = (float*)d_out;

    hipLaunchKernelGGL(k_stage1,   dim3(3072),        dim3(256), 0, stream,
                       pred, olabel, oconf, aconf, part, omean, amean);
    hipLaunchKernelGGL(k_sortmap,  dim3(NB),          dim3(64),  0, stream, part, omean, amean, srcmap);
    hipLaunchKernelGGL(k_assemble, dim3(64, 5, NB),   dim3(256), 0, stream,
                       oimage, aimage, olabel, alabel, oconf, aconf, srcmap, out);
}